// Round 6
// baseline (1235.631 us; speedup 1.0000x reference)
//
#include <hip/hip_runtime.h>
#include <hip/hip_fp16.h>

#define HID 32
#define BNODES 131     // nodes per bucket -> NB = ceil(100000/131) = 764 ~ 2.98 blocks/CU
#define NBP 768        // padded bucket count (3*256) for scan
#define BSTRIDE 4608   // per-bucket edge capacity: mean 4192, sigma~65 -> +6.4 sigma
#define CHUNK 4096     // edges per binscatter block

__device__ __forceinline__ float lrelu(float x) { return x > 0.0f ? x : 0.2f * x; }

// K1: layer-1 transform h1 = x @ W1 (f32 + f16), attention halves; zero bucket cursors.
__global__ void k_transform1(const float* __restrict__ x,
                             const float* __restrict__ W1,
                             const float* __restrict__ att_src,
                             const float* __restrict__ att_dst,
                             float* __restrict__ h,
                             __half* __restrict__ hh,
                             float* __restrict__ a_s,
                             float* __restrict__ a_d,
                             int* __restrict__ cursor,
                             int N)
{
    int tid = blockIdx.x * blockDim.x + threadIdx.x;
    if (tid < NBP) cursor[tid] = 0;
    int n = tid >> 5;
    int f = tid & 31;
    if (n >= N) return;
    float x0 = x[n * 3 + 0], x1 = x[n * 3 + 1], x2 = x[n * 3 + 2];
    float hv = x0 * W1[f] + x1 * W1[HID + f] + x2 * W1[2 * HID + f];
    h[(size_t)n * HID + f] = hv;
    hh[(size_t)n * HID + f] = __float2half(hv);
    float as = hv * att_src[f];
    float ad = hv * att_dst[f];
    #pragma unroll
    for (int m = 16; m >= 1; m >>= 1) {
        as += __shfl_xor(as, m, 32);
        ad += __shfl_xor(ad, m, 32);
    }
    if (f == 0) { a_s[n] = as; a_d[n] = ad; }
}

// K2: bin-scatter edges into fixed-capacity bucket regions (LDS-staged so the
// global writes are wave-coalesced runs — R4 showed direct scatter loses ~20us).
// packed u32: src (17b) | dstLocal (8b) << 17.
__global__ void __launch_bounds__(256) k_binscatter(const int* __restrict__ src,
                                                    const int* __restrict__ dst,
                                                    int* __restrict__ cursor,
                                                    unsigned int* __restrict__ packed,
                                                    int NB, int E)
{
    __shared__ int stage[CHUNK];
    __shared__ unsigned short bid[CHUNK];
    __shared__ int lhist[NBP], lexcl[NBP], lbase[NBP], lcur[NBP];
    __shared__ int arr[256];
    int t = threadIdx.x;
    for (int i = t; i < NBP; i += 256) { lhist[i] = 0; lcur[i] = 0; }
    __syncthreads();
    int base = blockIdx.x * CHUNK;
    int cnt = E - base; if (cnt > CHUNK) cnt = CHUNK;
    // pass 1: per-block bucket histogram
    for (int i = t; i < cnt; i += 256)
        atomicAdd(&lhist[dst[base + i] / BNODES], 1);
    __syncthreads();
    // scan: thread t owns buckets 3t..3t+2
    int b0 = 3 * t;
    int c0 = lhist[b0], c1 = lhist[b0 + 1], c2 = lhist[b0 + 2];
    int s = c0 + c1 + c2;
    arr[t] = s;
    __syncthreads();
    for (int o = 1; o < 256; o <<= 1) {
        int v = (t >= o) ? arr[t - o] : 0;
        __syncthreads();
        arr[t] += v;
        __syncthreads();
    }
    int excl = arr[t] - s;
    lexcl[b0] = excl; lexcl[b0 + 1] = excl + c0; lexcl[b0 + 2] = excl + c0 + c1;
    // reserve per-bucket global runs
    for (int b = t; b < NB; b += 256)
        lbase[b] = lhist[b] ? (b * BSTRIDE + atomicAdd(&cursor[b], lhist[b])) : 0;
    __syncthreads();
    // pass 2: sort chunk by bucket into stage
    for (int i = t; i < cnt; i += 256) {
        int d = dst[base + i];
        int sv = src[base + i];
        int b = d / BNODES;
        int dl = d - b * BNODES;
        int pos = atomicAdd(&lcur[b], 1);
        int idx = lexcl[b] + pos;
        stage[idx] = (int)((unsigned)sv | ((unsigned)dl << 17));
        bid[idx] = (unsigned short)b;
    }
    __syncthreads();
    // coalesced run writes
    for (int i = t; i < cnt; i += 256) {
        int b = bid[i];
        packed[lbase[b] + (i - lexcl[b])] = (unsigned)stage[i];
    }
}

// K3: bucketed aggregation layer 1. One block per bucket; LDS f32 accumulators
// (single pass: num and den together, divide at end). Epilogue: self-loop +
// b1 + ReLU + layer-2 transform + layer-2 attention halves.
__global__ void __launch_bounds__(512) k_agg1(const float* __restrict__ h,
                                              const __half* __restrict__ hh,
                                              const float* __restrict__ a_s,
                                              const float* __restrict__ a_d,
                                              const int* __restrict__ cursor,
                                              const unsigned int* __restrict__ packed,
                                              const float* __restrict__ b1,
                                              const float* __restrict__ W2,
                                              const float* __restrict__ as2w,
                                              const float* __restrict__ ad2w,
                                              float* __restrict__ h_out,
                                              __half* __restrict__ hh_out,
                                              float* __restrict__ as_out,
                                              float* __restrict__ ad_out,
                                              int N)
{
    __shared__ float acc[BNODES * 33];   // pad 33 breaks bank aliasing across nodes
    __shared__ float den[BNODES];
    __shared__ float adT[BNODES];
    int bk = blockIdx.x, t = threadIdx.x;
    int g = t >> 4, f = t & 15;
    int nb = bk * BNODES;
    for (int i = t; i < BNODES * 33; i += 512) acc[i] = 0.0f;
    for (int i = t; i < BNODES; i += 512) {
        den[i] = 0.0f;
        int n = nb + i;
        adT[i] = (n < N) ? a_d[n] : 0.0f;
    }
    __syncthreads();
    int cnt = cursor[bk]; if (cnt > BSTRIDE) cnt = BSTRIDE;
    const unsigned int* pk = packed + (size_t)bk * BSTRIDE;
    int i = g;
    for (; i + 32 < cnt; i += 64) {   // 2 independent gather chains per lane
        unsigned p0 = pk[i], p1 = pk[i + 32];
        int s0 = p0 & 0x1FFFF, d0 = (p0 >> 17) & 255;
        int s1 = p1 & 0x1FFFF, d1 = (p1 >> 17) & 255;
        float e0 = __expf(lrelu(a_s[s0] + adT[d0]));
        float e1 = __expf(lrelu(a_s[s1] + adT[d1]));
        float2 q0 = __half22float2(*(const __half2*)(hh + (size_t)s0 * HID + 2 * f));
        float2 q1 = __half22float2(*(const __half2*)(hh + (size_t)s1 * HID + 2 * f));
        atomicAdd(&acc[d0 * 33 + 2 * f], e0 * q0.x);
        atomicAdd(&acc[d0 * 33 + 2 * f + 1], e0 * q0.y);
        atomicAdd(&acc[d1 * 33 + 2 * f], e1 * q1.x);
        atomicAdd(&acc[d1 * 33 + 2 * f + 1], e1 * q1.y);
        if (f == 0) { atomicAdd(&den[d0], e0); atomicAdd(&den[d1], e1); }
    }
    for (; i < cnt; i += 32) {
        unsigned p0 = pk[i];
        int s0 = p0 & 0x1FFFF, d0 = (p0 >> 17) & 255;
        float e0 = __expf(lrelu(a_s[s0] + adT[d0]));
        float2 q0 = __half22float2(*(const __half2*)(hh + (size_t)s0 * HID + 2 * f));
        atomicAdd(&acc[d0 * 33 + 2 * f], e0 * q0.x);
        atomicAdd(&acc[d0 * 33 + 2 * f + 1], e0 * q0.y);
        if (f == 0) atomicAdd(&den[d0], e0);
    }
    __syncthreads();
    // pass A: finalize v = relu(softmax-agg + b1), store into acc rows
    for (int dl = g; dl < BNODES; dl += 32) {
        int n = nb + dl;
        if (n >= N) continue;
        float exs = __expf(lrelu(a_s[n] + adT[dl]));
        const float2 hs = *(const float2*)(h + (size_t)n * HID + 2 * f);
        float inv = 1.0f / (den[dl] + exs + 1e-16f);
        float vx = fmaxf(fmaf(exs, hs.x, acc[dl * 33 + 2 * f]) * inv + b1[2 * f], 0.0f);
        float vy = fmaxf(fmaf(exs, hs.y, acc[dl * 33 + 2 * f + 1]) * inv + b1[2 * f + 1], 0.0f);
        acc[dl * 33 + 2 * f] = vx;
        acc[dl * 33 + 2 * f + 1] = vy;
    }
    __syncthreads();
    // pass B: layer-2 transform + attention halves
    for (int dl = g; dl < BNODES; dl += 32) {
        int n = nb + dl;
        if (n >= N) continue;
        float hx = 0.0f, hy = 0.0f;
        #pragma unroll
        for (int k = 0; k < HID; ++k) {
            float vk = acc[dl * 33 + k];          // broadcast within group
            float2 w = *(const float2*)(W2 + k * HID + 2 * f);
            hx = fmaf(vk, w.x, hx);
            hy = fmaf(vk, w.y, hy);
        }
        *(float2*)(h_out + (size_t)n * HID + 2 * f) = make_float2(hx, hy);
        *(__half2*)(hh_out + (size_t)n * HID + 2 * f) = __floats2half2_rn(hx, hy);
        float as = hx * as2w[2 * f] + hy * as2w[2 * f + 1];
        float ad = hx * ad2w[2 * f] + hy * ad2w[2 * f + 1];
        #pragma unroll
        for (int m = 8; m >= 1; m >>= 1) {
            as += __shfl_xor(as, m, 16);
            ad += __shfl_xor(ad, m, 16);
        }
        if (f == 0) { as_out[n] = as; ad_out[n] = ad; }
    }
}

// K4: bucketed aggregation layer 2 + linear head.
__global__ void __launch_bounds__(512) k_agg2(const float* __restrict__ h,
                                              const __half* __restrict__ hh,
                                              const float* __restrict__ a_s,
                                              const float* __restrict__ a_d,
                                              const int* __restrict__ cursor,
                                              const unsigned int* __restrict__ packed,
                                              const float* __restrict__ b2,
                                              const float* __restrict__ Wl,
                                              const float* __restrict__ bl,
                                              float* __restrict__ out,
                                              int N)
{
    __shared__ float acc[BNODES * 33];
    __shared__ float den[BNODES];
    __shared__ float adT[BNODES];
    int bk = blockIdx.x, t = threadIdx.x;
    int g = t >> 4, f = t & 15;
    int nb = bk * BNODES;
    for (int i = t; i < BNODES * 33; i += 512) acc[i] = 0.0f;
    for (int i = t; i < BNODES; i += 512) {
        den[i] = 0.0f;
        int n = nb + i;
        adT[i] = (n < N) ? a_d[n] : 0.0f;
    }
    __syncthreads();
    int cnt = cursor[bk]; if (cnt > BSTRIDE) cnt = BSTRIDE;
    const unsigned int* pk = packed + (size_t)bk * BSTRIDE;
    int i = g;
    for (; i + 32 < cnt; i += 64) {
        unsigned p0 = pk[i], p1 = pk[i + 32];
        int s0 = p0 & 0x1FFFF, d0 = (p0 >> 17) & 255;
        int s1 = p1 & 0x1FFFF, d1 = (p1 >> 17) & 255;
        float e0 = __expf(lrelu(a_s[s0] + adT[d0]));
        float e1 = __expf(lrelu(a_s[s1] + adT[d1]));
        float2 q0 = __half22float2(*(const __half2*)(hh + (size_t)s0 * HID + 2 * f));
        float2 q1 = __half22float2(*(const __half2*)(hh + (size_t)s1 * HID + 2 * f));
        atomicAdd(&acc[d0 * 33 + 2 * f], e0 * q0.x);
        atomicAdd(&acc[d0 * 33 + 2 * f + 1], e0 * q0.y);
        atomicAdd(&acc[d1 * 33 + 2 * f], e1 * q1.x);
        atomicAdd(&acc[d1 * 33 + 2 * f + 1], e1 * q1.y);
        if (f == 0) { atomicAdd(&den[d0], e0); atomicAdd(&den[d1], e1); }
    }
    for (; i < cnt; i += 32) {
        unsigned p0 = pk[i];
        int s0 = p0 & 0x1FFFF, d0 = (p0 >> 17) & 255;
        float e0 = __expf(lrelu(a_s[s0] + adT[d0]));
        float2 q0 = __half22float2(*(const __half2*)(hh + (size_t)s0 * HID + 2 * f));
        atomicAdd(&acc[d0 * 33 + 2 * f], e0 * q0.x);
        atomicAdd(&acc[d0 * 33 + 2 * f + 1], e0 * q0.y);
        if (f == 0) atomicAdd(&den[d0], e0);
    }
    __syncthreads();
    for (int dl = g; dl < BNODES; dl += 32) {
        int n = nb + dl;
        if (n >= N) continue;
        float exs = __expf(lrelu(a_s[n] + adT[dl]));
        const float2 hs = *(const float2*)(h + (size_t)n * HID + 2 * f);
        float inv = 1.0f / (den[dl] + exs + 1e-16f);
        float vx = fmaxf(fmaf(exs, hs.x, acc[dl * 33 + 2 * f]) * inv + b2[2 * f], 0.0f);
        float vy = fmaxf(fmaf(exs, hs.y, acc[dl * 33 + 2 * f + 1]) * inv + b2[2 * f + 1], 0.0f);
        float y = vx * Wl[2 * f] + vy * Wl[2 * f + 1];
        #pragma unroll
        for (int m = 8; m >= 1; m >>= 1)
            y += __shfl_xor(y, m, 16);
        if (f == 0) out[n] = y + bl[0];
    }
}

extern "C" void kernel_launch(void* const* d_in, const int* in_sizes, int n_in,
                              void* d_out, int out_size, void* d_ws, size_t ws_size,
                              hipStream_t stream)
{
    const float* x        = (const float*)d_in[0];
    const int*   eidx     = (const int*)d_in[1];
    const float* W1       = (const float*)d_in[2];
    const float* att_src1 = (const float*)d_in[3];
    const float* att_dst1 = (const float*)d_in[4];
    const float* b1       = (const float*)d_in[5];
    const float* W2       = (const float*)d_in[6];
    const float* att_src2 = (const float*)d_in[7];
    const float* att_dst2 = (const float*)d_in[8];
    const float* b2       = (const float*)d_in[9];
    const float* Wl       = (const float*)d_in[10];
    const float* bl       = (const float*)d_in[11];
    float* out = (float*)d_out;

    int N = in_sizes[0] / 3;
    int E = in_sizes[1] / 2;
    const int* src = eidx;
    const int* dst = eidx + E;
    int NB = (N + BNODES - 1) / BNODES;   // 764

    size_t szNH  = (size_t)N * HID * 4;   // 12.8 MB
    size_t szNHh = (size_t)N * HID * 2;   // 6.4 MB
    size_t szN4  = (size_t)N * 4;
    size_t szPK  = (size_t)NB * BSTRIDE * 4;  // 13.4 MB

    char* ws = (char*)d_ws;
    float*  h1     = (float*)ws;  ws += szNH;
    float*  h2     = (float*)ws;  ws += szNH;
    __half* h1h    = (__half*)ws; ws += szNHh;
    __half* h2h    = (__half*)ws; ws += szNHh;
    unsigned int* packed = (unsigned int*)ws; ws += szPK;
    float*  a_s1   = (float*)ws;  ws += szN4;
    float*  a_d1   = (float*)ws;  ws += szN4;
    float*  a_s2   = (float*)ws;  ws += szN4;
    float*  a_d2   = (float*)ws;  ws += szN4;
    int*    cursor = (int*)ws;    ws += NBP * 4;

    const int B = 256;
    int gridNode32 = (N * HID + B - 1) / B;
    int gridBin    = (E + CHUNK - 1) / CHUNK;

    k_transform1<<<gridNode32, B, 0, stream>>>(x, W1, att_src1, att_dst1,
                                               h1, h1h, a_s1, a_d1, cursor, N);
    k_binscatter<<<gridBin, B, 0, stream>>>(src, dst, cursor, packed, NB, E);
    k_agg1<<<NB, 512, 0, stream>>>(h1, h1h, a_s1, a_d1, cursor, packed,
                                   b1, W2, att_src2, att_dst2,
                                   h2, h2h, a_s2, a_d2, N);
    k_agg2<<<NB, 512, 0, stream>>>(h2, h2h, a_s2, a_d2, cursor, packed,
                                   b2, Wl, bl, out, N);
}

// Round 7
// 272.437 us; speedup vs baseline: 4.5355x; 4.5355x over previous
//
#include <hip/hip_runtime.h>
#include <hip/hip_fp16.h>

#define HID 32
#define BN 132         // nodes per bucket -> NB = ceil(100000/132) = 758
#define NBPAD 1024     // padded bucket arrays (4 per thread in scan)
#define BSTRIDE 5120   // per-bucket edge capacity: mean 4224, sigma ~65 -> +13.8 sigma
#define CHUNK 8192     // edges per binscatter block (391 blocks, all resident at 3/CU)

__device__ __forceinline__ float lrelu(float x) { return x > 0.0f ? x : 0.2f * x; }

// K1: layer-1 transform h1 = x @ W1 (f16), attention halves; zero bucket cursors.
__global__ void k_transform1(const float* __restrict__ x,
                             const float* __restrict__ W1,
                             const float* __restrict__ att_src,
                             const float* __restrict__ att_dst,
                             __half* __restrict__ hh,
                             float* __restrict__ a_s,
                             float* __restrict__ a_d,
                             int* __restrict__ cursor,
                             int N)
{
    int tid = blockIdx.x * blockDim.x + threadIdx.x;
    if (tid < NBPAD) cursor[tid] = 0;
    int n = tid >> 5;
    int f = tid & 31;
    if (n >= N) return;
    float x0 = x[n * 3 + 0], x1 = x[n * 3 + 1], x2 = x[n * 3 + 2];
    float hv = x0 * W1[f] + x1 * W1[HID + f] + x2 * W1[2 * HID + f];
    hh[(size_t)n * HID + f] = __float2half(hv);
    float as = hv * att_src[f];
    float ad = hv * att_dst[f];
    #pragma unroll
    for (int m = 16; m >= 1; m >>= 1) {
        as += __shfl_xor(as, m, 32);
        ad += __shfl_xor(ad, m, 32);
    }
    if (f == 0) { a_s[n] = as; a_d[n] = ad; }
}

// K2: bin-scatter edges into fixed-capacity bucket regions. LDS-staged (R4
// showed direct scatter loses ~20us to uncoalesced stores). Bucket of a stage
// slot is recovered via binary search over lexcl (saves the 16KB bid array).
// packed u32: src (17b) | dstLocal (8b) << 17.
__global__ void __launch_bounds__(256) k_binscatter(const int* __restrict__ src,
                                                    const int* __restrict__ dst,
                                                    int* __restrict__ cursor,
                                                    unsigned int* __restrict__ packed,
                                                    int NB, int E)
{
    __shared__ int stage[CHUNK];                                   // 32 KB
    __shared__ int lhist[NBPAD], lexcl[NBPAD], lbase[NBPAD], lcur[NBPAD]; // 16 KB
    __shared__ int arr[256];
    int t = threadIdx.x;
    for (int i = t; i < NBPAD; i += 256) { lhist[i] = 0; lcur[i] = 0; }
    __syncthreads();
    int base = blockIdx.x * CHUNK;
    int cnt = E - base; if (cnt > CHUNK) cnt = CHUNK;
    // pass 1: per-block bucket histogram
    for (int i = t; i < cnt; i += 256)
        atomicAdd(&lhist[dst[base + i] / BN], 1);
    __syncthreads();
    // block-local exclusive scan, 4 buckets per thread
    int b0 = 4 * t;
    int c0 = lhist[b0], c1 = lhist[b0 + 1], c2 = lhist[b0 + 2], c3 = lhist[b0 + 3];
    int s = c0 + c1 + c2 + c3;
    arr[t] = s;
    __syncthreads();
    for (int o = 1; o < 256; o <<= 1) {
        int v = (t >= o) ? arr[t - o] : 0;
        __syncthreads();
        arr[t] += v;
        __syncthreads();
    }
    int ex = arr[t] - s;
    lexcl[b0] = ex; lexcl[b0 + 1] = ex + c0;
    lexcl[b0 + 2] = ex + c0 + c1; lexcl[b0 + 3] = ex + c0 + c1 + c2;
    // reserve per-bucket global runs
    for (int b = t; b < NB; b += 256)
        if (lhist[b]) lbase[b] = b * BSTRIDE + atomicAdd(&cursor[b], lhist[b]);
    __syncthreads();
    // pass 2: sort chunk by bucket into stage
    for (int i = t; i < cnt; i += 256) {
        int d = dst[base + i];
        int sv = src[base + i];
        int b = d / BN;
        int dl = d - b * BN;
        int idx = lexcl[b] + atomicAdd(&lcur[b], 1);
        stage[idx] = (int)((unsigned)sv | ((unsigned)dl << 17));
    }
    __syncthreads();
    // coalesced run writes; bucket of slot i = last b with lexcl[b] <= i
    for (int i = t; i < cnt; i += 256) {
        int lo = 0, hi = NB - 1;
        while (lo < hi) {
            int mid = (lo + hi + 1) >> 1;
            if (lexcl[mid] <= i) lo = mid; else hi = mid - 1;
        }
        int gpos = lbase[lo] + (i - lexcl[lo]);
        if (gpos < (lo + 1) * BSTRIDE)
            packed[gpos] = (unsigned)stage[i];
    }
}

// K3: per-bucket CSR build in LDS, written back IN PLACE (csr aliases packed:
// all reads of the window precede the writes within this block). 22 KB LDS.
__global__ void __launch_bounds__(256) k_bucket_csr(unsigned int* __restrict__ packed,
                                                    const int* __restrict__ cursor,
                                                    int* __restrict__ offsets,
                                                    int* __restrict__ deg, int N)
{
    __shared__ int lcsr[BSTRIDE];   // 20 KB
    __shared__ int lhist[256], lscan[256], lcur[256];
    int b = blockIdx.x, t = threadIdx.x;
    int base = b * BSTRIDE;
    int cnt = cursor[b]; if (cnt > BSTRIDE) cnt = BSTRIDE;
    lhist[t] = 0; lcur[t] = 0;
    __syncthreads();
    for (int i = t; i < cnt; i += 256)
        atomicAdd(&lhist[(packed[base + i] >> 17) & 255], 1);
    __syncthreads();
    lscan[t] = lhist[t];
    __syncthreads();
    for (int o = 1; o < 256; o <<= 1) {
        int v = (t >= o) ? lscan[t - o] : 0;
        __syncthreads();
        lscan[t] += v;
        __syncthreads();
    }
    int node = b * BN + t;
    int excl = lscan[t] - lhist[t];
    if (t < BN && node < N) { offsets[node] = base + excl; deg[node] = lhist[t]; }
    for (int i = t; i < cnt; i += 256) {
        unsigned int p = packed[base + i];
        int dl = (p >> 17) & 255;
        int pos = atomicAdd(&lcur[dl], 1);
        lcsr[(lscan[dl] - lhist[dl]) + pos] = (int)(p & 0x1FFFF);
    }
    __syncthreads();
    for (int i = t; i < cnt; i += 256)
        packed[base + i] = (unsigned)lcsr[i];   // in-place: packed becomes csr
}

// Aggregation core: 16 lanes per node, lane f owns features {2f, 2f+1}.
// Gather unrolled x8 for memory-level parallelism. Self term in f16 too.
__device__ __forceinline__ void agg_core(const __half* __restrict__ hh,
                                         const float* __restrict__ a_s,
                                         float a_dn, float a_sn,
                                         const float* __restrict__ b,
                                         int n, int f, int off, int dg,
                                         const int* __restrict__ csr_src,
                                         float& vx, float& vy)
{
    float ex = __expf(lrelu(a_sn + a_dn));
    float den = ex;
    float2 hs = __half22float2(*(const __half2*)(hh + (size_t)n * HID + 2 * f));
    float accx = ex * hs.x;
    float accy = ex * hs.y;
    for (int base = 0; base < dg; base += 16) {
        int m = dg - base; if (m > 16) m = 16;
        int sv = 0;
        float exv = 0.0f;
        if (f < m) {
            sv = csr_src[off + base + f];
            exv = __expf(lrelu(a_s[sv] + a_dn));
        }
        int j = 0;
        for (; j + 8 <= m; j += 8) {
            int s0 = __shfl(sv, j, 16), s1 = __shfl(sv, j + 1, 16);
            int s2 = __shfl(sv, j + 2, 16), s3 = __shfl(sv, j + 3, 16);
            int s4 = __shfl(sv, j + 4, 16), s5 = __shfl(sv, j + 5, 16);
            int s6 = __shfl(sv, j + 6, 16), s7 = __shfl(sv, j + 7, 16);
            float e0 = __shfl(exv, j, 16), e1 = __shfl(exv, j + 1, 16);
            float e2 = __shfl(exv, j + 2, 16), e3 = __shfl(exv, j + 3, 16);
            float e4 = __shfl(exv, j + 4, 16), e5 = __shfl(exv, j + 5, 16);
            float e6 = __shfl(exv, j + 6, 16), e7 = __shfl(exv, j + 7, 16);
            __half2 p0 = *(const __half2*)(hh + (size_t)s0 * HID + 2 * f);
            __half2 p1 = *(const __half2*)(hh + (size_t)s1 * HID + 2 * f);
            __half2 p2 = *(const __half2*)(hh + (size_t)s2 * HID + 2 * f);
            __half2 p3 = *(const __half2*)(hh + (size_t)s3 * HID + 2 * f);
            __half2 p4 = *(const __half2*)(hh + (size_t)s4 * HID + 2 * f);
            __half2 p5 = *(const __half2*)(hh + (size_t)s5 * HID + 2 * f);
            __half2 p6 = *(const __half2*)(hh + (size_t)s6 * HID + 2 * f);
            __half2 p7 = *(const __half2*)(hh + (size_t)s7 * HID + 2 * f);
            float2 q0 = __half22float2(p0), q1 = __half22float2(p1);
            float2 q2 = __half22float2(p2), q3 = __half22float2(p3);
            float2 q4 = __half22float2(p4), q5 = __half22float2(p5);
            float2 q6 = __half22float2(p6), q7 = __half22float2(p7);
            den += ((e0 + e1) + (e2 + e3)) + ((e4 + e5) + (e6 + e7));
            accx = fmaf(e0, q0.x, accx); accy = fmaf(e0, q0.y, accy);
            accx = fmaf(e1, q1.x, accx); accy = fmaf(e1, q1.y, accy);
            accx = fmaf(e2, q2.x, accx); accy = fmaf(e2, q2.y, accy);
            accx = fmaf(e3, q3.x, accx); accy = fmaf(e3, q3.y, accy);
            accx = fmaf(e4, q4.x, accx); accy = fmaf(e4, q4.y, accy);
            accx = fmaf(e5, q5.x, accx); accy = fmaf(e5, q5.y, accy);
            accx = fmaf(e6, q6.x, accx); accy = fmaf(e6, q6.y, accy);
            accx = fmaf(e7, q7.x, accx); accy = fmaf(e7, q7.y, accy);
        }
        for (; j + 4 <= m; j += 4) {
            int s0 = __shfl(sv, j, 16), s1 = __shfl(sv, j + 1, 16);
            int s2 = __shfl(sv, j + 2, 16), s3 = __shfl(sv, j + 3, 16);
            float e0 = __shfl(exv, j, 16), e1 = __shfl(exv, j + 1, 16);
            float e2 = __shfl(exv, j + 2, 16), e3 = __shfl(exv, j + 3, 16);
            __half2 p0 = *(const __half2*)(hh + (size_t)s0 * HID + 2 * f);
            __half2 p1 = *(const __half2*)(hh + (size_t)s1 * HID + 2 * f);
            __half2 p2 = *(const __half2*)(hh + (size_t)s2 * HID + 2 * f);
            __half2 p3 = *(const __half2*)(hh + (size_t)s3 * HID + 2 * f);
            float2 q0 = __half22float2(p0), q1 = __half22float2(p1);
            float2 q2 = __half22float2(p2), q3 = __half22float2(p3);
            den += (e0 + e1) + (e2 + e3);
            accx = fmaf(e0, q0.x, accx); accy = fmaf(e0, q0.y, accy);
            accx = fmaf(e1, q1.x, accx); accy = fmaf(e1, q1.y, accy);
            accx = fmaf(e2, q2.x, accx); accy = fmaf(e2, q2.y, accy);
            accx = fmaf(e3, q3.x, accx); accy = fmaf(e3, q3.y, accy);
        }
        for (; j < m; ++j) {
            int s0 = __shfl(sv, j, 16);
            float e0 = __shfl(exv, j, 16);
            float2 q0 = __half22float2(*(const __half2*)(hh + (size_t)s0 * HID + 2 * f));
            den += e0;
            accx = fmaf(e0, q0.x, accx);
            accy = fmaf(e0, q0.y, accy);
        }
    }
    float inv = 1.0f / (den + 1e-16f);
    vx = fmaxf(accx * inv + b[2 * f], 0.0f);
    vy = fmaxf(accy * inv + b[2 * f + 1], 0.0f);
}

// K4: layer-1 aggregate + b1 + ReLU, fused with layer-2 transform + attention halves.
__global__ void __launch_bounds__(256) k_agg_mid(const __half* __restrict__ hh,
                          const float* __restrict__ a_s,
                          const float* __restrict__ a_d,
                          const int* __restrict__ offsets,
                          const int* __restrict__ deg,
                          const int* __restrict__ csr_src,
                          const float* __restrict__ b,
                          const float* __restrict__ W2,
                          const float* __restrict__ att_src2,
                          const float* __restrict__ att_dst2,
                          __half* __restrict__ hh_out,
                          float* __restrict__ a_s_out,
                          float* __restrict__ a_d_out,
                          int N)
{
    int tid = blockIdx.x * blockDim.x + threadIdx.x;
    int n = tid >> 4;
    int f = tid & 15;
    if (n >= N) return;
    float vx, vy;
    agg_core(hh, a_s, a_d[n], a_s[n], b, n, f, offsets[n], deg[n], csr_src, vx, vy);
    float hx = 0.0f, hy = 0.0f;
    #pragma unroll
    for (int k = 0; k < 16; ++k) {
        float va = __shfl(vx, k, 16);   // v[2k]
        float vb = __shfl(vy, k, 16);   // v[2k+1]
        float2 w0 = *(const float2*)(W2 + (2 * k) * HID + 2 * f);
        float2 w1 = *(const float2*)(W2 + (2 * k + 1) * HID + 2 * f);
        hx = fmaf(va, w0.x, hx); hy = fmaf(va, w0.y, hy);
        hx = fmaf(vb, w1.x, hx); hy = fmaf(vb, w1.y, hy);
    }
    *(__half2*)(hh_out + (size_t)n * HID + 2 * f) = __floats2half2_rn(hx, hy);
    float as = hx * att_src2[2 * f] + hy * att_src2[2 * f + 1];
    float ad = hx * att_dst2[2 * f] + hy * att_dst2[2 * f + 1];
    #pragma unroll
    for (int m2 = 8; m2 >= 1; m2 >>= 1) {
        as += __shfl_xor(as, m2, 16);
        ad += __shfl_xor(ad, m2, 16);
    }
    if (f == 0) { a_s_out[n] = as; a_d_out[n] = ad; }
}

// K5: layer-2 aggregate + b2 + ReLU, fused with linear head + bl.
__global__ void __launch_bounds__(256) k_agg_out(const __half* __restrict__ hh,
                          const float* __restrict__ a_s,
                          const float* __restrict__ a_d,
                          const int* __restrict__ offsets,
                          const int* __restrict__ deg,
                          const int* __restrict__ csr_src,
                          const float* __restrict__ b,
                          const float* __restrict__ Wl,
                          const float* __restrict__ bl,
                          float* __restrict__ out,
                          int N)
{
    int tid = blockIdx.x * blockDim.x + threadIdx.x;
    int n = tid >> 4;
    int f = tid & 15;
    if (n >= N) return;
    float vx, vy;
    agg_core(hh, a_s, a_d[n], a_s[n], b, n, f, offsets[n], deg[n], csr_src, vx, vy);
    float y = vx * Wl[2 * f] + vy * Wl[2 * f + 1];
    #pragma unroll
    for (int m2 = 8; m2 >= 1; m2 >>= 1) {
        y += __shfl_xor(y, m2, 16);
    }
    if (f == 0) out[n] = y + bl[0];
}

extern "C" void kernel_launch(void* const* d_in, const int* in_sizes, int n_in,
                              void* d_out, int out_size, void* d_ws, size_t ws_size,
                              hipStream_t stream)
{
    const float* x        = (const float*)d_in[0];
    const int*   eidx     = (const int*)d_in[1];
    const float* W1       = (const float*)d_in[2];
    const float* att_src1 = (const float*)d_in[3];
    const float* att_dst1 = (const float*)d_in[4];
    const float* b1       = (const float*)d_in[5];
    const float* W2       = (const float*)d_in[6];
    const float* att_src2 = (const float*)d_in[7];
    const float* att_dst2 = (const float*)d_in[8];
    const float* b2       = (const float*)d_in[9];
    const float* Wl       = (const float*)d_in[10];
    const float* bl       = (const float*)d_in[11];
    float* out = (float*)d_out;

    int N = in_sizes[0] / 3;
    int E = in_sizes[1] / 2;
    const int* src = eidx;
    const int* dst = eidx + E;
    int NB = (N + BN - 1) / BN;   // 758

    size_t szNHh = (size_t)N * HID * 2;          // 6.4 MB
    size_t szN4  = (size_t)N * 4;
    size_t szPK  = (size_t)NB * BSTRIDE * 4;     // 15.5 MB

    char* ws = (char*)d_ws;
    __half* h1h    = (__half*)ws; ws += szNHh;
    __half* h2h    = (__half*)ws; ws += szNHh;
    unsigned int* packed = (unsigned int*)ws; ws += szPK;  // becomes csr in-place
    float*  a_s1   = (float*)ws;  ws += szN4;
    float*  a_d1   = (float*)ws;  ws += szN4;
    float*  a_s2   = (float*)ws;  ws += szN4;
    float*  a_d2   = (float*)ws;  ws += szN4;
    int*    deg    = (int*)ws;    ws += szN4;
    int*    offsets= (int*)ws;    ws += szN4;
    int*    cursor = (int*)ws;    ws += NBPAD * 4;

    const int B = 256;
    int gridNode32 = (N * HID + B - 1) / B;
    int gridNode16 = (N * 16 + B - 1) / B;
    int gridBin    = (E + CHUNK - 1) / CHUNK;

    k_transform1<<<gridNode32, B, 0, stream>>>(x, W1, att_src1, att_dst1,
                                               h1h, a_s1, a_d1, cursor, N);
    k_binscatter<<<gridBin, B, 0, stream>>>(src, dst, cursor, packed, NB, E);
    k_bucket_csr<<<NB, B, 0, stream>>>(packed, cursor, offsets, deg, N);
    k_agg_mid<<<gridNode16, B, 0, stream>>>(h1h, a_s1, a_d1, offsets, deg, (const int*)packed,
                                            b1, W2, att_src2, att_dst2,
                                            h2h, a_s2, a_d2, N);
    k_agg_out<<<gridNode16, B, 0, stream>>>(h2h, a_s2, a_d2, offsets, deg, (const int*)packed,
                                            b2, Wl, bl, out, N);
}

// Round 8
// 259.684 us; speedup vs baseline: 4.7582x; 1.0491x over previous
//
#include <hip/hip_runtime.h>
#include <hip/hip_fp16.h>

#define HID 32
#define BN 132         // nodes per bucket -> NB = ceil(100000/132) = 758
#define NBPAD 768      // padded bucket arrays (3 per thread in binscatter scan)
#define BSTRIDE 5120   // per-bucket edge capacity: mean 4224, sigma ~65 -> +13.8 sigma
#define CHUNK 4096     // edges per binscatter block -> 782 blocks ~ 3.05/CU

__device__ __forceinline__ float lrelu(float x) { return x > 0.0f ? x : 0.2f * x; }

// K1: layer-1 transform h1 = x @ W1 (f16), attention halves; zero bucket cursors.
__global__ void k_transform1(const float* __restrict__ x,
                             const float* __restrict__ W1,
                             const float* __restrict__ att_src,
                             const float* __restrict__ att_dst,
                             __half* __restrict__ hh,
                             float* __restrict__ a_s,
                             float* __restrict__ a_d,
                             int* __restrict__ cursor,
                             int N)
{
    int tid = blockIdx.x * blockDim.x + threadIdx.x;
    if (tid < NBPAD) cursor[tid] = 0;
    int n = tid >> 5;
    int f = tid & 31;
    if (n >= N) return;
    float x0 = x[n * 3 + 0], x1 = x[n * 3 + 1], x2 = x[n * 3 + 2];
    float hv = x0 * W1[f] + x1 * W1[HID + f] + x2 * W1[2 * HID + f];
    hh[(size_t)n * HID + f] = __float2half(hv);
    float as = hv * att_src[f];
    float ad = hv * att_dst[f];
    #pragma unroll
    for (int m = 16; m >= 1; m >>= 1) {
        as += __shfl_xor(as, m, 32);
        ad += __shfl_xor(ad, m, 32);
    }
    if (f == 0) { a_s[n] = as; a_d[n] = ad; }
}

// K2: bin-scatter edges into fixed-capacity bucket regions. LDS-staged for
// coalesced run writes; slot->bucket map (sbid) filled contiguously by each
// bucket's owner thread (replaces R6's binary search -> fewer LDS conflicts).
// packed u32: src (17b) | dstLocal (8b) << 17.
__global__ void __launch_bounds__(256) k_binscatter(const int* __restrict__ src,
                                                    const int* __restrict__ dst,
                                                    int* __restrict__ cursor,
                                                    unsigned int* __restrict__ packed,
                                                    int NBr, int E)
{
    __shared__ int stage[CHUNK];                  // 16 KB
    __shared__ unsigned short sbid[CHUNK];        // 8 KB
    __shared__ int lhist[NBPAD], lexcl[NBPAD], lbase[NBPAD], lcur[NBPAD]; // 12 KB
    __shared__ int arr[256];
    int t = threadIdx.x;
    for (int i = t; i < NBPAD; i += 256) { lhist[i] = 0; lcur[i] = 0; }
    __syncthreads();
    int base = blockIdx.x * CHUNK;
    int cnt = E - base; if (cnt > CHUNK) cnt = CHUNK;
    // pass 1: per-block bucket histogram
    for (int i = t; i < cnt; i += 256)
        atomicAdd(&lhist[dst[base + i] / BN], 1);
    __syncthreads();
    // block-local exclusive scan, 3 buckets per thread (3*256 = 768 >= NB)
    int b0 = 3 * t;
    int c0 = lhist[b0], c1 = lhist[b0 + 1], c2 = lhist[b0 + 2];
    int s = c0 + c1 + c2;
    arr[t] = s;
    __syncthreads();
    for (int o = 1; o < 256; o <<= 1) {
        int v = (t >= o) ? arr[t - o] : 0;
        __syncthreads();
        arr[t] += v;
        __syncthreads();
    }
    int ex = arr[t] - s;
    int e0 = ex, e1 = ex + c0, e2 = ex + c0 + c1;
    lexcl[b0] = e0; lexcl[b0 + 1] = e1; lexcl[b0 + 2] = e2;
    // fill slot->bucket map for owned buckets (contiguous LDS writes)
    for (int i = 0; i < c0; ++i) sbid[e0 + i] = (unsigned short)b0;
    for (int i = 0; i < c1; ++i) sbid[e1 + i] = (unsigned short)(b0 + 1);
    for (int i = 0; i < c2; ++i) sbid[e2 + i] = (unsigned short)(b0 + 2);
    // reserve per-bucket global runs
    for (int b = t; b < NBr; b += 256)
        if (lhist[b]) lbase[b] = b * BSTRIDE + atomicAdd(&cursor[b], lhist[b]);
    __syncthreads();
    // pass 2: sort chunk by bucket into stage
    for (int i = t; i < cnt; i += 256) {
        int d = dst[base + i];
        int sv = src[base + i];
        int b = d / BN;
        int dl = d - b * BN;
        int idx = lexcl[b] + atomicAdd(&lcur[b], 1);
        stage[idx] = (int)((unsigned)sv | ((unsigned)dl << 17));
    }
    __syncthreads();
    // coalesced run writes
    for (int i = t; i < cnt; i += 256) {
        int b = sbid[i];
        int gpos = lbase[b] + (i - lexcl[b]);
        if (gpos < (b + 1) * BSTRIDE)
            packed[gpos] = (unsigned)stage[i];
    }
}

// Per-node aggregation: 16 lanes per node, lane f owns features {2f, 2f+1},
// edge list read from LDS (lcsr). Gather unrolled x8 for MLP latency hiding.
__device__ __forceinline__ void agg_node(const __half* __restrict__ hh,
                                         const float* __restrict__ a_s,
                                         float a_dn, float a_sn,
                                         const float* __restrict__ b,
                                         int n, int f,
                                         const int* lcsr, int off, int dg,
                                         float& vx, float& vy)
{
    float ex = __expf(lrelu(a_sn + a_dn));
    float den = ex;
    float2 hs = __half22float2(*(const __half2*)(hh + (size_t)n * HID + 2 * f));
    float accx = ex * hs.x;
    float accy = ex * hs.y;
    for (int base = 0; base < dg; base += 16) {
        int m = dg - base; if (m > 16) m = 16;
        int sv = 0;
        float exv = 0.0f;
        if (f < m) {
            sv = lcsr[off + base + f];
            exv = __expf(lrelu(a_s[sv] + a_dn));
        }
        int j = 0;
        for (; j + 8 <= m; j += 8) {
            int s0 = __shfl(sv, j, 16), s1 = __shfl(sv, j + 1, 16);
            int s2 = __shfl(sv, j + 2, 16), s3 = __shfl(sv, j + 3, 16);
            int s4 = __shfl(sv, j + 4, 16), s5 = __shfl(sv, j + 5, 16);
            int s6 = __shfl(sv, j + 6, 16), s7 = __shfl(sv, j + 7, 16);
            float e0 = __shfl(exv, j, 16), e1 = __shfl(exv, j + 1, 16);
            float e2 = __shfl(exv, j + 2, 16), e3 = __shfl(exv, j + 3, 16);
            float e4 = __shfl(exv, j + 4, 16), e5 = __shfl(exv, j + 5, 16);
            float e6 = __shfl(exv, j + 6, 16), e7 = __shfl(exv, j + 7, 16);
            __half2 p0 = *(const __half2*)(hh + (size_t)s0 * HID + 2 * f);
            __half2 p1 = *(const __half2*)(hh + (size_t)s1 * HID + 2 * f);
            __half2 p2 = *(const __half2*)(hh + (size_t)s2 * HID + 2 * f);
            __half2 p3 = *(const __half2*)(hh + (size_t)s3 * HID + 2 * f);
            __half2 p4 = *(const __half2*)(hh + (size_t)s4 * HID + 2 * f);
            __half2 p5 = *(const __half2*)(hh + (size_t)s5 * HID + 2 * f);
            __half2 p6 = *(const __half2*)(hh + (size_t)s6 * HID + 2 * f);
            __half2 p7 = *(const __half2*)(hh + (size_t)s7 * HID + 2 * f);
            float2 q0 = __half22float2(p0), q1 = __half22float2(p1);
            float2 q2 = __half22float2(p2), q3 = __half22float2(p3);
            float2 q4 = __half22float2(p4), q5 = __half22float2(p5);
            float2 q6 = __half22float2(p6), q7 = __half22float2(p7);
            den += ((e0 + e1) + (e2 + e3)) + ((e4 + e5) + (e6 + e7));
            accx = fmaf(e0, q0.x, accx); accy = fmaf(e0, q0.y, accy);
            accx = fmaf(e1, q1.x, accx); accy = fmaf(e1, q1.y, accy);
            accx = fmaf(e2, q2.x, accx); accy = fmaf(e2, q2.y, accy);
            accx = fmaf(e3, q3.x, accx); accy = fmaf(e3, q3.y, accy);
            accx = fmaf(e4, q4.x, accx); accy = fmaf(e4, q4.y, accy);
            accx = fmaf(e5, q5.x, accx); accy = fmaf(e5, q5.y, accy);
            accx = fmaf(e6, q6.x, accx); accy = fmaf(e6, q6.y, accy);
            accx = fmaf(e7, q7.x, accx); accy = fmaf(e7, q7.y, accy);
        }
        for (; j + 4 <= m; j += 4) {
            int s0 = __shfl(sv, j, 16), s1 = __shfl(sv, j + 1, 16);
            int s2 = __shfl(sv, j + 2, 16), s3 = __shfl(sv, j + 3, 16);
            float e0 = __shfl(exv, j, 16), e1 = __shfl(exv, j + 1, 16);
            float e2 = __shfl(exv, j + 2, 16), e3 = __shfl(exv, j + 3, 16);
            __half2 p0 = *(const __half2*)(hh + (size_t)s0 * HID + 2 * f);
            __half2 p1 = *(const __half2*)(hh + (size_t)s1 * HID + 2 * f);
            __half2 p2 = *(const __half2*)(hh + (size_t)s2 * HID + 2 * f);
            __half2 p3 = *(const __half2*)(hh + (size_t)s3 * HID + 2 * f);
            float2 q0 = __half22float2(p0), q1 = __half22float2(p1);
            float2 q2 = __half22float2(p2), q3 = __half22float2(p3);
            den += (e0 + e1) + (e2 + e3);
            accx = fmaf(e0, q0.x, accx); accy = fmaf(e0, q0.y, accy);
            accx = fmaf(e1, q1.x, accx); accy = fmaf(e1, q1.y, accy);
            accx = fmaf(e2, q2.x, accx); accy = fmaf(e2, q2.y, accy);
            accx = fmaf(e3, q3.x, accx); accy = fmaf(e3, q3.y, accy);
        }
        for (; j < m; ++j) {
            int s0 = __shfl(sv, j, 16);
            float e0 = __shfl(exv, j, 16);
            float2 q0 = __half22float2(*(const __half2*)(hh + (size_t)s0 * HID + 2 * f));
            den += e0;
            accx = fmaf(e0, q0.x, accx);
            accy = fmaf(e0, q0.y, accy);
        }
    }
    float inv = 1.0f / (den + 1e-16f);
    vx = fmaxf(accx * inv + b[2 * f], 0.0f);
    vy = fmaxf(accy * inv + b[2 * f + 1], 0.0f);
}

// In-block CSR build: bucket's packed window -> node-sorted lcsr (LDS).
// lhist/lscan retained for per-node off/deg. 512 threads.
__device__ __forceinline__ int build_lcsr(const unsigned int* pk, int cnt,
                                          int* lcsr, int* lhist, int* lscan, int* lcur)
{
    int t = threadIdx.x;
    if (t < 256) { lhist[t] = 0; lcur[t] = 0; }
    __syncthreads();
    for (int i = t; i < cnt; i += 512)
        atomicAdd(&lhist[(pk[i] >> 17) & 255], 1);
    __syncthreads();
    if (t < 256) lscan[t] = lhist[t];
    __syncthreads();
    for (int o = 1; o < 256; o <<= 1) {
        int v = (t < 256 && t >= o) ? lscan[t - o] : 0;
        __syncthreads();
        if (t < 256) lscan[t] += v;
        __syncthreads();
    }
    for (int i = t; i < cnt; i += 512) {
        unsigned int p = pk[i];
        int dl = (p >> 17) & 255;
        int pos = atomicAdd(&lcur[dl], 1);
        lcsr[(lscan[dl] - lhist[dl]) + pos] = (int)(p & 0x1FFFF);
    }
    __syncthreads();
    return cnt;
}

// K3: fused CSR-build + layer-1 aggregate + b1 + ReLU + layer-2 transform
//     + layer-2 attention halves. One block per bucket, 512 threads.
__global__ void __launch_bounds__(512) k_agg_mid_f(const __half* __restrict__ hh,
                          const float* __restrict__ a_s,
                          const float* __restrict__ a_d,
                          const int* __restrict__ cursor,
                          const unsigned int* __restrict__ packed,
                          const float* __restrict__ b1,
                          const float* __restrict__ W2,
                          const float* __restrict__ as2w,
                          const float* __restrict__ ad2w,
                          __half* __restrict__ hh_out,
                          float* __restrict__ as_out,
                          float* __restrict__ ad_out,
                          int N)
{
    __shared__ int lcsr[BSTRIDE];                       // 20 KB
    __shared__ int lhist[256], lscan[256], lcur[256];   // 3 KB
    int bk = blockIdx.x, t = threadIdx.x;
    int cnt = cursor[bk]; if (cnt > BSTRIDE) cnt = BSTRIDE;
    build_lcsr(packed + (size_t)bk * BSTRIDE, cnt, lcsr, lhist, lscan, lcur);
    int g = t >> 4, f = t & 15;
    for (int dl = g; dl < BN; dl += 32) {
        int n = bk * BN + dl;
        if (n >= N) continue;                 // group-uniform
        int off = lscan[dl] - lhist[dl];
        int dg = lhist[dl];
        float vx, vy;
        agg_node(hh, a_s, a_d[n], a_s[n], b1, n, f, lcsr, off, dg, vx, vy);
        float hx = 0.0f, hy = 0.0f;
        #pragma unroll
        for (int k = 0; k < 16; ++k) {
            float va = __shfl(vx, k, 16);     // v[2k]
            float vb = __shfl(vy, k, 16);     // v[2k+1]
            float2 w0 = *(const float2*)(W2 + (2 * k) * HID + 2 * f);
            float2 w1 = *(const float2*)(W2 + (2 * k + 1) * HID + 2 * f);
            hx = fmaf(va, w0.x, hx); hy = fmaf(va, w0.y, hy);
            hx = fmaf(vb, w1.x, hx); hy = fmaf(vb, w1.y, hy);
        }
        *(__half2*)(hh_out + (size_t)n * HID + 2 * f) = __floats2half2_rn(hx, hy);
        float as = hx * as2w[2 * f] + hy * as2w[2 * f + 1];
        float ad = hx * ad2w[2 * f] + hy * ad2w[2 * f + 1];
        #pragma unroll
        for (int m2 = 8; m2 >= 1; m2 >>= 1) {
            as += __shfl_xor(as, m2, 16);
            ad += __shfl_xor(ad, m2, 16);
        }
        if (f == 0) { as_out[n] = as; ad_out[n] = ad; }
    }
}

// K4: fused CSR-build + layer-2 aggregate + b2 + ReLU + linear head + bl.
__global__ void __launch_bounds__(512) k_agg_out_f(const __half* __restrict__ hh,
                          const float* __restrict__ a_s,
                          const float* __restrict__ a_d,
                          const int* __restrict__ cursor,
                          const unsigned int* __restrict__ packed,
                          const float* __restrict__ b2,
                          const float* __restrict__ Wl,
                          const float* __restrict__ bl,
                          float* __restrict__ out,
                          int N)
{
    __shared__ int lcsr[BSTRIDE];
    __shared__ int lhist[256], lscan[256], lcur[256];
    int bk = blockIdx.x, t = threadIdx.x;
    int cnt = cursor[bk]; if (cnt > BSTRIDE) cnt = BSTRIDE;
    build_lcsr(packed + (size_t)bk * BSTRIDE, cnt, lcsr, lhist, lscan, lcur);
    int g = t >> 4, f = t & 15;
    for (int dl = g; dl < BN; dl += 32) {
        int n = bk * BN + dl;
        if (n >= N) continue;
        int off = lscan[dl] - lhist[dl];
        int dg = lhist[dl];
        float vx, vy;
        agg_node(hh, a_s, a_d[n], a_s[n], b2, n, f, lcsr, off, dg, vx, vy);
        float y = vx * Wl[2 * f] + vy * Wl[2 * f + 1];
        #pragma unroll
        for (int m2 = 8; m2 >= 1; m2 >>= 1)
            y += __shfl_xor(y, m2, 16);
        if (f == 0) out[n] = y + bl[0];
    }
}

extern "C" void kernel_launch(void* const* d_in, const int* in_sizes, int n_in,
                              void* d_out, int out_size, void* d_ws, size_t ws_size,
                              hipStream_t stream)
{
    const float* x        = (const float*)d_in[0];
    const int*   eidx     = (const int*)d_in[1];
    const float* W1       = (const float*)d_in[2];
    const float* att_src1 = (const float*)d_in[3];
    const float* att_dst1 = (const float*)d_in[4];
    const float* b1       = (const float*)d_in[5];
    const float* W2       = (const float*)d_in[6];
    const float* att_src2 = (const float*)d_in[7];
    const float* att_dst2 = (const float*)d_in[8];
    const float* b2       = (const float*)d_in[9];
    const float* Wl       = (const float*)d_in[10];
    const float* bl       = (const float*)d_in[11];
    float* out = (float*)d_out;

    int N = in_sizes[0] / 3;
    int E = in_sizes[1] / 2;
    const int* src = eidx;
    const int* dst = eidx + E;
    int NBr = (N + BN - 1) / BN;   // 758

    size_t szNHh = (size_t)N * HID * 2;          // 6.4 MB
    size_t szN4  = (size_t)N * 4;
    size_t szPK  = (size_t)NBr * BSTRIDE * 4;    // 15.5 MB

    char* ws = (char*)d_ws;
    __half* h1h    = (__half*)ws; ws += szNHh;
    __half* h2h    = (__half*)ws; ws += szNHh;
    unsigned int* packed = (unsigned int*)ws; ws += szPK;
    float*  a_s1   = (float*)ws;  ws += szN4;
    float*  a_d1   = (float*)ws;  ws += szN4;
    float*  a_s2   = (float*)ws;  ws += szN4;
    float*  a_d2   = (float*)ws;  ws += szN4;
    int*    cursor = (int*)ws;    ws += NBPAD * 4;

    const int B = 256;
    int gridNode32 = (N * HID + B - 1) / B;
    int gridBin    = (E + CHUNK - 1) / CHUNK;

    k_transform1<<<gridNode32, B, 0, stream>>>(x, W1, att_src1, att_dst1,
                                               h1h, a_s1, a_d1, cursor, N);
    k_binscatter<<<gridBin, B, 0, stream>>>(src, dst, cursor, packed, NBr, E);
    k_agg_mid_f<<<NBr, 512, 0, stream>>>(h1h, a_s1, a_d1, cursor, packed,
                                         b1, W2, att_src2, att_dst2,
                                         h2h, a_s2, a_d2, N);
    k_agg_out_f<<<NBr, 512, 0, stream>>>(h2h, a_s2, a_d2, cursor, packed,
                                         b2, Wl, bl, out, N);
}